// Round 2
// 164.763 us; speedup vs baseline: 1.0139x; 1.0139x over previous
//
#include <hip/hip_runtime.h>
#include <math.h>

#define BB 256
#define SSEQ 128
#define INPUT 256
#define PD 128
#define EE 64
#define RW 256
#define MM 512
#define WW 64
#define KD 384          // IN_DIM

typedef _Float16 half8 __attribute__((ext_vector_type(8)));
typedef __fp16 fp16x2 __attribute__((ext_vector_type(2)));
typedef float float4v __attribute__((ext_vector_type(4)));
typedef float f32x16 __attribute__((ext_vector_type(16)));
typedef unsigned int uint2v __attribute__((ext_vector_type(2)));

#define LOG2E 1.44269504088896f
#define OUT1 8388608u

// LDS byte layout.
// Phase A (prologue): [0,128K) = Wq x-part f16 image, chunk c = (k>>3)*256 + n.
// Phase B (flash):    [0,64K)  = mem f16 rows (chunk m*8 + (c^(m&7))),
//                     [64K,128K) = memT f16 (chunk w*64 + (cm^(w&7))).
// [128K, 128K+6K) f32 scratch.
#define MEMT_OFF 65536
#define MEMT16   4096            // MEMT_OFF in uint4 units
#define F32_OFF  131072
#define LDS_BYTES (131072 + 6144)
#define UE_O 0
#define PE_O 64
#define QPE_O 192
#define QP_O 448                  // qpart [1024]

union H8 { half8 h8; unsigned int u[4]; uint4 u4; };

__device__ __forceinline__ unsigned int pk2(float a, float b) {
    union { fp16x2 h; unsigned int u; } p;
    p.h = __builtin_amdgcn_cvt_pkrtz(a, b);
    return p.u;
}

// v_permlane32_swap_b32 via the builtin (NOT inline asm: two "+v" asm operands
// holding the same value can be coalesced into ONE physical VGPR -> self-swap
// garbage. That was R1's absmax=4.6e7 failure.)
// returns r[0] = [a_lo | b_lo], r[1] = [a_hi | b_hi]
__device__ __forceinline__ float xhalf_max(float v) {
    uint2v r = __builtin_amdgcn_permlane32_swap(__float_as_uint(v), __float_as_uint(v), false, false);
    return fmaxf(__uint_as_float(r[0]), __uint_as_float(r[1]));
}
__device__ __forceinline__ float xhalf_sum(float v) {
    uint2v r = __builtin_amdgcn_permlane32_swap(__float_as_uint(v), __float_as_uint(v), false, false);
    return __uint_as_float(r[0]) + __uint_as_float(r[1]);
}

// ---------- single fused kernel: 256 blocks x 1024 threads (16 waves) ----------
// HARD-WON CONSTRAINTS (do not violate):
//  * launch_bounds (1024,4): forcing (1024,8) = 64-reg cap -> spills (R7, 2x slower).
//  * No multi-pass restructure of the flash loop (R8: spills, 4x slower).
//  * NEVER store/read MFMA accumulators (Sa) inside the loop beyond the exp/pack
//    path (R8/R9: forces accs into VGPR quads -> spill -> occupancy 6%).
// Flash loop uses 32x32x16 MFMA, swapped-operand layout:
//  lane = (s = lane&31, hh = lane>>5); Sa regs hold 16 of 32 m-rows per s-col
//  (partner half in lane^32). ALL in-loop cross-lane traffic goes through
//  v_permlane32_swap_b32 (VALU) -- zero ds_bpermute/ds_swizzle in the loop.
__global__ void __launch_bounds__(1024, 4)
attn_kernel(const float* __restrict__ x, const int* __restrict__ user_id,
            const float* __restrict__ uet, const float* __restrict__ W_proc,
            const float* __restrict__ b_proc, const float* __restrict__ Wq,
            const float* __restrict__ memG, float* __restrict__ out)
{
    extern __shared__ char smraw[];
    unsigned short* smemu = (unsigned short*)smraw;
    unsigned int*   smw   = (unsigned int*)smraw;
    uint4*          sm128 = (uint4*)smraw;
    float*          smf   = (float*)(smraw + F32_OFF);

    const int t = threadIdx.x;
    const int b = blockIdx.x;
    const int lane = t & 63, wv = t >> 6;        // 16 waves
    const int n16 = lane & 15, quad = lane >> 4;
    const int l31 = lane & 31, hh = lane >> 5;
    const int r = wv & 3, sq = wv >> 2;          // sq 0..3
    const int s0 = sq * 32;
    const int mswz = l31 & 7;

    const int uid = user_id[b];
    const int sid = uid & 15;
    const float* memB = memG + (size_t)sid * (MM*WW);
    const float* wqX  = Wq + (size_t)sid * KD * RW;

    if (t < EE) smf[UE_O + t] = uet[(size_t)uid*EE + t];

    // ---- Prologue A: Wq x-part (k<256, n<256) -> LDS f16 image [k/8][n][k%8] ----
    for (int i = 0; i < 32; ++i) {
        int idx = i*1024 + t;                    // 0..32767
        int n = idx & 255, kp = idx >> 8;        // kp = k/2
        float w0 = wqX[(size_t)(2*kp)    *RW + n];
        float w1 = wqX[(size_t)(2*kp + 1)*RW + n];
        smw[((((kp>>2)*256 + n) << 2) | (kp & 3))] = pk2(w0, w1);
    }
    __syncthreads();

    // pe
    if (t < PD) {
        float a = b_proc[t];
        #pragma unroll
        for (int e = 0; e < EE; ++e) a = fmaf(smf[UE_O + e], W_proc[e*PD + t], a);
        smf[PE_O + t] = a;
    }
    __syncthreads();
    // qpe partials
    {
        int n = t & 255, h = t >> 8;
        float s = 0.f;
        const float* wr = wqX + (size_t)(256 + h*32)*RW + n;
        #pragma unroll 8
        for (int k = 0; k < 32; ++k) s = fmaf(smf[PE_O + h*32 + k], wr[(size_t)k*RW], s);
        smf[QP_O + h*256 + n] = s;
    }
    __syncthreads();
    if (t < 256) smf[QPE_O + t] = LOG2E * (smf[QP_O + t] + smf[QP_O + 256 + t]
                                         + smf[QP_O + 512 + t] + smf[QP_O + 768 + t]);
    __syncthreads();

    // ---- Phase Q (x-part k<256 only; pe via qpe bias; kc MUST stop at 8) ----
    float4v qacc[4][2];
    #pragma unroll
    for (int mt = 0; mt < 4; ++mt)
        #pragma unroll
        for (int nt = 0; nt < 2; ++nt) qacc[mt][nt] = (float4v)0.f;

    const float* xB = x + (size_t)(b*SSEQ + s0) * INPUT;
    for (int kc = 0; kc < 8; ++kc) {
        H8 afr[4];
        #pragma unroll
        for (int mt = 0; mt < 4; ++mt)
            afr[mt].u4 = sm128[(kc*4 + quad)*256 + r*64 + mt*16 + n16];
        H8 bfr[2];
        #pragma unroll
        for (int nt = 0; nt < 2; ++nt) {
            const float* xg = xB + (size_t)(nt*16 + n16)*INPUT + kc*32 + quad*8;
            float4 a0 = *(const float4*)xg;
            float4 a1 = *(const float4*)(xg + 4);
            bfr[nt].u[0] = pk2(a0.x*LOG2E, a0.y*LOG2E);
            bfr[nt].u[1] = pk2(a0.z*LOG2E, a0.w*LOG2E);
            bfr[nt].u[2] = pk2(a1.x*LOG2E, a1.y*LOG2E);
            bfr[nt].u[3] = pk2(a1.z*LOG2E, a1.w*LOG2E);
        }
        #pragma unroll
        for (int mt = 0; mt < 4; ++mt)
            #pragma unroll
            for (int nt = 0; nt < 2; ++nt)
                qacc[mt][nt] = __builtin_amdgcn_mfma_f32_16x16x32_f16(afr[mt].h8, bfr[nt].h8, qacc[mt][nt], 0, 0, 0);
    }
    #pragma unroll
    for (int mt = 0; mt < 4; ++mt)
        #pragma unroll
        for (int reg = 0; reg < 4; ++reg) {
            float qv = smf[QPE_O + r*64 + mt*16 + quad*4 + reg];
            #pragma unroll
            for (int nt = 0; nt < 2; ++nt) qacc[mt][nt][reg] += qv;
        }
    unsigned int pkq[4][2][2];
    #pragma unroll
    for (int mt = 0; mt < 4; ++mt)
        #pragma unroll
        for (int nt = 0; nt < 2; ++nt) {
            pkq[mt][nt][0] = pk2(qacc[mt][nt][0], qacc[mt][nt][1]);
            pkq[mt][nt][1] = pk2(qacc[mt][nt][2], qacc[mt][nt][3]);
        }
    // ---- repack q into 32x32x16 B-operand layout (one-time) ----
    // target lane (s5 = lane&31, hh): bqf[kc].u[jp] = f16pair q[n = kc*16 + hh*8 + 2jp + {0,1}][s0+s5]
    H8 bqf[4];
    {
        const int ntSel = (lane >> 4) & 1;           // = bit4 of s5
        const int srcBase = (lane & 15) + (lane & 32);
        #pragma unroll
        for (int kc = 0; kc < 4; ++kc)
            #pragma unroll
            for (int jp = 0; jp < 4; ++jp) {
                const int src = srcBase + ((jp >> 1) << 4);
                int v0 = __shfl((int)pkq[kc][0][jp & 1], src, 64);
                int v1 = __shfl((int)pkq[kc][1][jp & 1], src, 64);
                bqf[kc].u[jp] = (unsigned int)(ntSel ? v1 : v0);
            }
    }
    __syncthreads();                             // all waves done reading Wq image

    // ---- Prologue B: overwrite LDS with mem f16 images (convert + transpose) ----
    for (int i = 0; i < 4; ++i) {
        int id = t + i*1024;
        int m = id >> 3, cw = id & 7;
        const float* g = memB + m*64 + cw*8;
        float4 a0 = *(const float4*)g;
        float4 a1 = *(const float4*)(g + 4);
        sm128[m*8 + (cw ^ (m & 7))] =
            make_uint4(pk2(a0.x,a0.y), pk2(a0.z,a0.w), pk2(a1.x,a1.y), pk2(a1.z,a1.w));
    }
    __syncthreads();
    for (int i = 0; i < 4; ++i) {
        int id = t + i*1024;
        int w = id & 63, cm = id >> 6;
        unsigned int uu[4];
        #pragma unroll
        for (int p = 0; p < 4; ++p) {
            int m0 = cm*8 + 2*p, m1 = m0 + 1;
            unsigned short lo = smemu[m0*64 + (((w>>3) ^ (m0&7))<<3) + (w&7)];
            unsigned short hi = smemu[m1*64 + (((w>>3) ^ (m1&7))<<3) + (w&7)];
            uu[p] = (unsigned int)lo | ((unsigned int)hi << 16);
        }
        sm128[MEMT16 + w*64 + (cm ^ (w & 7))] = make_uint4(uu[0],uu[1],uu[2],uu[3]);
    }
    __syncthreads();

    // ========== single-pass flash loop: 32x32x16, permlane-only cross-lane ==========
    f32x16 Oa0 = (f32x16)0.f, Oa1 = (f32x16)0.f;
    float Ml = -1e30f, llp = 0.f;

    for (int mtile = 0; mtile < 16; ++mtile) {
        // QK: A = mem rows (m = mtile*32 + l31), B = q; Sa C-layout:
        //   col s = l31, row m_local = (g&3) + 8*(g>>2) + 4*hh
        f32x16 Sa = (f32x16)0.f;
        const int mrow = mtile*32 + l31;
        #pragma unroll
        for (int kc = 0; kc < 4; ++kc) {
            H8 af; af.u4 = sm128[mrow*8 + (((kc<<1) + hh) ^ mswz)];
            Sa = __builtin_amdgcn_mfma_f32_32x32x16_f16(af.h8, bqf[kc].h8, Sa, 0, 0, 0);
        }
        // row max over 32 m for this s-col: in-reg tree + one permlane swap
        float tma = fmaxf(fmaxf(fmaxf(Sa[0],Sa[1]), fmaxf(Sa[2],Sa[3])),
                          fmaxf(fmaxf(Sa[4],Sa[5]), fmaxf(Sa[6],Sa[7])));
        float tmb = fmaxf(fmaxf(fmaxf(Sa[8],Sa[9]), fmaxf(Sa[10],Sa[11])),
                          fmaxf(fmaxf(Sa[12],Sa[13]), fmaxf(Sa[14],Sa[15])));
        float tm = xhalf_max(fmaxf(tma, tmb));
        float Mn = fmaxf(Ml, tm);
        float al = __builtin_amdgcn_exp2f(Ml - Mn);
        float pv[16];
        #pragma unroll
        for (int g = 0; g < 16; ++g) pv[g] = __builtin_amdgcn_exp2f(Sa[g] - Mn);
        float ts = (((pv[0]+pv[1])+(pv[2]+pv[3])) + ((pv[4]+pv[5])+(pv[6]+pv[7])))
                 + (((pv[8]+pv[9])+(pv[10]+pv[11])) + ((pv[12]+pv[13])+(pv[14]+pv[15])));
        llp = al*llp + ts;                       // per-lane partial; combined at end
        Ml = Mn;
        #pragma unroll
        for (int g = 0; g < 16; ++g) { Oa0[g] *= al; Oa1[g] *= al; }
        // P -> PV B-operand: pack pairs, 2 swaps per 16-m half (T12 pattern)
        uint2v rA0 = __builtin_amdgcn_permlane32_swap(pk2(pv[0],pv[1]),   pk2(pv[4],pv[5]),   false, false);
        uint2v rB0 = __builtin_amdgcn_permlane32_swap(pk2(pv[2],pv[3]),   pk2(pv[6],pv[7]),   false, false);
        uint2v rA1 = __builtin_amdgcn_permlane32_swap(pk2(pv[8],pv[9]),   pk2(pv[12],pv[13]), false, false);
        uint2v rB1 = __builtin_amdgcn_permlane32_swap(pk2(pv[10],pv[11]), pk2(pv[14],pv[15]), false, false);
        H8 bp0; bp0.u[0]=rA0[0]; bp0.u[1]=rB0[0]; bp0.u[2]=rA0[1]; bp0.u[3]=rB0[1];
        H8 bp1; bp1.u[0]=rA1[0]; bp1.u[1]=rB1[0]; bp1.u[2]=rA1[1]; bp1.u[3]=rB1[1];
        // PV: A = memT rows (w), k = m; Oa C-layout: col s = l31,
        //   w_local = (g&3) + 8*(g>>2) + 4*hh (+ 32 for Oa1)
        const int c0 = mtile*4 + hh;
        {
            H8 af0; af0.u4 = sm128[MEMT16 + l31*64        + ( c0      ^ mswz)];
            Oa0 = __builtin_amdgcn_mfma_f32_32x32x16_f16(af0.h8, bp0.h8, Oa0, 0, 0, 0);
            H8 af1; af1.u4 = sm128[MEMT16 + l31*64        + ((c0 + 2) ^ mswz)];
            Oa0 = __builtin_amdgcn_mfma_f32_32x32x16_f16(af1.h8, bp1.h8, Oa0, 0, 0, 0);
            H8 af2; af2.u4 = sm128[MEMT16 + (32 + l31)*64 + ( c0      ^ mswz)];
            Oa1 = __builtin_amdgcn_mfma_f32_32x32x16_f16(af2.h8, bp0.h8, Oa1, 0, 0, 0);
            H8 af3; af3.u4 = sm128[MEMT16 + (32 + l31)*64 + ((c0 + 2) ^ mswz)];
            Oa1 = __builtin_amdgcn_mfma_f32_32x32x16_f16(af3.h8, bp1.h8, Oa1, 0, 0, 0);
        }
    }

    // combine the two half-partials of the denominator (lane <-> lane^32)
    float inv = 1.0f / xhalf_sum(llp);

    // ---- store read_words ----
    {
        const int s = s0 + l31;
        float* op = out + ((size_t)(b*SSEQ + s)*4 + r)*WW;
        #pragma unroll
        for (int rq = 0; rq < 4; ++rq) {
            float4 o0 = make_float4(Oa0[rq*4+0]*inv, Oa0[rq*4+1]*inv,
                                    Oa0[rq*4+2]*inv, Oa0[rq*4+3]*inv);
            *(float4*)&op[rq*8 + hh*4] = o0;
            float4 o1 = make_float4(Oa1[rq*4+0]*inv, Oa1[rq*4+1]*inv,
                                    Oa1[rq*4+2]*inv, Oa1[rq*4+3]*inv);
            *(float4*)&op[32 + rq*8 + hh*4] = o1;
        }
    }

    // ---- final_state (b == 255): recompute scores, store normalized wts ----
    if (b == BB - 1) {
        const int s = s0 + l31;
        size_t base = (size_t)OUT1 + ((size_t)(s*4 + r) << 9);
        for (int mtile = 0; mtile < 16; ++mtile) {
            f32x16 Sa = (f32x16)0.f;
            const int mrow = mtile*32 + l31;
            #pragma unroll
            for (int kc = 0; kc < 4; ++kc) {
                H8 af; af.u4 = sm128[mrow*8 + (((kc<<1) + hh) ^ mswz)];
                Sa = __builtin_amdgcn_mfma_f32_32x32x16_f16(af.h8, bqf[kc].h8, Sa, 0, 0, 0);
            }
            #pragma unroll
            for (int rq = 0; rq < 4; ++rq) {
                float4 w4 = make_float4(
                    __builtin_amdgcn_exp2f(Sa[rq*4+0] - Ml) * inv,
                    __builtin_amdgcn_exp2f(Sa[rq*4+1] - Ml) * inv,
                    __builtin_amdgcn_exp2f(Sa[rq*4+2] - Ml) * inv,
                    __builtin_amdgcn_exp2f(Sa[rq*4+3] - Ml) * inv);
                *(float4*)&out[base + mtile*32 + rq*8 + hh*4] = w4;
            }
        }
    }
}

extern "C" void kernel_launch(void* const* d_in, const int* in_sizes, int n_in,
                              void* d_out, int out_size, void* d_ws, size_t ws_size,
                              hipStream_t stream) {
    const float* x    = (const float*)d_in[0];
    const int*   uid  = (const int*)  d_in[1];
    const float* uet  = (const float*)d_in[2];
    const float* Wp   = (const float*)d_in[3];
    const float* bp   = (const float*)d_in[4];
    const float* Wq   = (const float*)d_in[5];
    const float* mem  = (const float*)d_in[6];
    float* out = (float*)d_out;

    (void)hipFuncSetAttribute((const void*)attn_kernel,
                              hipFuncAttributeMaxDynamicSharedMemorySize, LDS_BYTES);
    attn_kernel<<<BB, 1024, LDS_BYTES, stream>>>(x, uid, uet, Wp, bp, Wq, mem, out);
}